// Round 8
// baseline (464.735 us; speedup 1.0000x reference)
//
#include <hip/hip_runtime.h>
#include <cstddef>
#include <cstdint>

typedef float f2    __attribute__((ext_vector_type(2)));
typedef float f32x4 __attribute__((ext_vector_type(4)));
typedef short bf16x8 __attribute__((ext_vector_type(8)));

__device__ __forceinline__ float fast_exp2(float x) { return __builtin_amdgcn_exp2f(x); }
__device__ __forceinline__ float fast_log2(float x) { return __builtin_amdgcn_logf(x); }

__device__ __forceinline__ short bf16rne(float x) {
  uint32_t u = __float_as_uint(x);
  u += 0x7fffu + ((u >> 16) & 1u);
  return (short)(u >> 16);
}

// LDS-only barrier: no vmcnt drain, global prefetch stays in flight.
__device__ __forceinline__ void bar_lds() {
  asm volatile("s_waitcnt lgkmcnt(0)\n\ts_barrier" ::: "memory");
}

namespace {
constexpr int Bc = 256, Tc = 1024, Kc = 128;
constexpr int ROWS = 16;
constexpr int HALF = Tc / 2;              // 512
constexpr float L2E = 1.4426950408889634f;
constexpr float LN2 = 0.6931471805599453f;
constexpr int PSTR = 136;
// ws floats: PF[256][128], PB[256][128], MIF[256], MIB[256]
constexpr int WS_PB  = Bc * Kc;
constexpr int WS_MIF = 2 * Bc * Kc;
constexpr int WS_MIB = WS_MIF + Bc;
}

// 16 blocks x 256 threads. Block rb runs BOTH directions for batch rows
// 16rb..16rb+15, software-pipelined half a step apart:
//   phase A: issue fwd matvec k   | complete bwd step k (epi+publish) | bar | read
//   phase B: issue bwd matvec k+1 | complete fwd step k               | bar | read
// Each chain's exchange latency hides under the other chain's MFMA/VALU;
// the two barriers per pair are SHARED (1 per chain-step, same as R7).
// bwd needs 512 matvecs (511 steps + final v=Ew) — the phase shift
// provides the extra matvec naturally. Per-chain math identical to R7
// (lag-1 exact pow2 rescale, bf16 exchange, ring prefetch).
__global__ __launch_bounds__(256, 1) void crf_fwd_bwd_kernel(
    const float* __restrict__ hs,
    const float* __restrict__ trans,
    const float* __restrict__ start_t,
    const float* __restrict__ end_t,
    float* __restrict__ ws)
{
  __shared__ __align__(16) unsigned short pLF[2][ROWS][PSTR];
  __shared__ __align__(16) unsigned short pLG[2][ROWS][PSTR];
  __shared__ float sScF[2][ROWS], sScG[2][ROWS];

  const int tid = (int)threadIdx.x;
  const int w = tid >> 6;
  const int lane = tid & 63;
  const int b = lane & 15;
  const int kq = lane >> 4;
  const int rb = (int)blockIdx.x;
  const int brow = rb * ROWS + b;
  const float* __restrict__ eb = hs + (size_t)brow * Tc * Kc;

  const int jb0 = 32 * w + 4 * kq;
  const int jb1 = 32 * w + 16 + 4 * kq;

  // A-frags: AF = E^T (fwd), AG = E (bwd). MFMA reads them from AGPRs.
  bf16x8 AF[2][4], AG[2][4];
#pragma unroll
  for (int np = 0; np < 2; ++np)
#pragma unroll
    for (int tt = 0; tt < 4; ++tt) {
      bf16x8 af, ag;
#pragma unroll
      for (int jj = 0; jj < 8; ++jj) {
        const int kg = 32 * tt + 8 * kq + jj;
        const int rg = 16 * (2 * w + np) + b;
        af[jj] = bf16rne(fast_exp2(trans[(size_t)kg * Kc + rg] * L2E));
        ag[jj] = bf16rne(fast_exp2(trans[(size_t)rg * Kc + kg] * L2E));
      }
      AF[np][tt] = af;
      AG[np][tt] = ag;
    }

  // Emission rings. Fwd slot d: row 1+d. Bwd slot d: row 1022-d.
  f32x4 erF[4][2], erG[4][2];
#pragma unroll
  for (int d = 0; d < 4; ++d) {
    erF[d][0] = *(const f32x4*)&eb[(size_t)(1 + d) * Kc + jb0];
    erF[d][1] = *(const f32x4*)&eb[(size_t)(1 + d) * Kc + jb1];
    erG[d][0] = *(const f32x4*)&eb[(size_t)(1022 - d) * Kc + jb0];
    erG[d][1] = *(const f32x4*)&eb[(size_t)(1022 - d) * Kc + jb1];
  }

  // Init vectors: fwd 2^((start+e_0)L2E); bwd 2^((end+e_1023)L2E). Buf 0.
#pragma unroll
  for (int np = 0; np < 2; ++np) {
    const int jb = np ? jb1 : jb0;
    f32x4 sv = *(const f32x4*)&start_t[jb];
    f32x4 e0 = *(const f32x4*)&eb[jb];
    uint32_t d0 = (uint32_t)(uint16_t)bf16rne(fast_exp2((sv.x + e0.x) * L2E)) |
                  ((uint32_t)(uint16_t)bf16rne(fast_exp2((sv.y + e0.y) * L2E)) << 16);
    uint32_t d1 = (uint32_t)(uint16_t)bf16rne(fast_exp2((sv.z + e0.z) * L2E)) |
                  ((uint32_t)(uint16_t)bf16rne(fast_exp2((sv.w + e0.w) * L2E)) << 16);
    *(uint2*)&pLF[0][b][jb] = make_uint2(d0, d1);
    sv = *(const f32x4*)&end_t[jb];
    e0 = *(const f32x4*)&eb[(size_t)(Tc - 1) * Kc + jb];
    d0 = (uint32_t)(uint16_t)bf16rne(fast_exp2((sv.x + e0.x) * L2E)) |
         ((uint32_t)(uint16_t)bf16rne(fast_exp2((sv.y + e0.y) * L2E)) << 16);
    d1 = (uint32_t)(uint16_t)bf16rne(fast_exp2((sv.z + e0.z) * L2E)) |
         ((uint32_t)(uint16_t)bf16rne(fast_exp2((sv.w + e0.w) * L2E)) << 16);
    *(uint2*)&pLG[0][b][jb] = make_uint2(d0, d1);
  }
  bar_lds();
  bf16x8 BfF[4], BfG[4];
#pragma unroll
  for (int tt = 0; tt < 4; ++tt) {
    BfF[tt] = *(const bf16x8*)&pLF[0][b][32 * tt + 8 * kq];
    BfG[tt] = *(const bf16x8*)&pLG[0][b][32 * tt + 8 * kq];
  }

  float scaleF = 1.0f, scaleG = 1.0f;
  int e0F = 0, e0G = 0, MiF = 0, MiG = 0;
  f32x4 pf0 = {0, 0, 0, 0}, pf1 = {0, 0, 0, 0};

  auto matvec = [&](const bf16x8 (&A)[2][4], const bf16x8 (&Bf)[4], f32x4* C) {
#pragma unroll
    for (int np = 0; np < 2; ++np) {
      f32x4 c01 = __builtin_amdgcn_mfma_f32_16x16x32_bf16(
          A[np][1], Bf[1],
          __builtin_amdgcn_mfma_f32_16x16x32_bf16(A[np][0], Bf[0],
                                                  (f32x4){0.f, 0.f, 0.f, 0.f}, 0, 0, 0),
          0, 0, 0);
      f32x4 c23 = __builtin_amdgcn_mfma_f32_16x16x32_bf16(
          A[np][3], Bf[3],
          __builtin_amdgcn_mfma_f32_16x16x32_bf16(A[np][2], Bf[2],
                                                  (f32x4){0.f, 0.f, 0.f, 0.f}, 0, 0, 0),
          0, 0, 0);
      C[np] = c01 + c23;
    }
  };

  f32x4 CG[2];
  matvec(AG, BfG, CG);   // bwd matvec #1 (pipeline prime)

  auto step_pair = [&](int k, int u) {
    const int buf = k & 1;
    // ---- phase A: fwd matvec k issues; bwd step k completes ----
    f32x4 CF[2];
    matvec(AF, BfF, CF);
    {
      f32x4 e = erG[u][0];
      f32x4 se0, se1;
      se0.x = scaleG * fast_exp2(e.x * L2E); se0.y = scaleG * fast_exp2(e.y * L2E);
      se0.z = scaleG * fast_exp2(e.z * L2E); se0.w = scaleG * fast_exp2(e.w * L2E);
      e = erG[u][1];
      se1.x = scaleG * fast_exp2(e.x * L2E); se1.y = scaleG * fast_exp2(e.y * L2E);
      se1.z = scaleG * fast_exp2(e.z * L2E); se1.w = scaleG * fast_exp2(e.w * L2E);
      MiG += e0G;
      int rn = 1019 - k; if (rn < HALF) rn = HALF;
      erG[u][0] = *(const f32x4*)&eb[(size_t)rn * Kc + jb0];
      erG[u][1] = *(const f32x4*)&eb[(size_t)rn * Kc + jb1];
      f32x4 p;
      p.x = CG[0].x * se0.x; p.y = CG[0].y * se0.y;
      p.z = CG[0].z * se0.z; p.w = CG[0].w * se0.w;
      uint32_t d0 = (uint32_t)(uint16_t)bf16rne(p.x) | ((uint32_t)(uint16_t)bf16rne(p.y) << 16);
      uint32_t d1 = (uint32_t)(uint16_t)bf16rne(p.z) | ((uint32_t)(uint16_t)bf16rne(p.w) << 16);
      *(uint2*)&pLG[buf][b][jb0] = make_uint2(d0, d1);
      p.x = CG[1].x * se1.x; p.y = CG[1].y * se1.y;
      p.z = CG[1].z * se1.z; p.w = CG[1].w * se1.w;
      d0 = (uint32_t)(uint16_t)bf16rne(p.x) | ((uint32_t)(uint16_t)bf16rne(p.y) << 16);
      d1 = (uint32_t)(uint16_t)bf16rne(p.z) | ((uint32_t)(uint16_t)bf16rne(p.w) << 16);
      *(uint2*)&pLG[buf][b][jb1] = make_uint2(d0, d1);
      if (w == 0 && kq == 0) sScG[buf][b] = CG[0].x;
    }
    bar_lds();
#pragma unroll
    for (int tt = 0; tt < 4; ++tt)
      BfG[tt] = *(const bf16x8*)&pLG[buf][b][32 * tt + 8 * kq];
    {
      uint32_t ex = (__float_as_uint(sScG[buf][b]) >> 23) & 0xffu;
      e0G = (int)ex - 127;
      scaleG = __uint_as_float((254u - ex) << 23);
    }
    // ---- phase B: bwd matvec k+1 issues; fwd step k completes ----
    matvec(AG, BfG, CG);
    {
      f32x4 e = erF[u][0];
      f32x4 se0, se1;
      se0.x = scaleF * fast_exp2(e.x * L2E); se0.y = scaleF * fast_exp2(e.y * L2E);
      se0.z = scaleF * fast_exp2(e.z * L2E); se0.w = scaleF * fast_exp2(e.w * L2E);
      e = erF[u][1];
      se1.x = scaleF * fast_exp2(e.x * L2E); se1.y = scaleF * fast_exp2(e.y * L2E);
      se1.z = scaleF * fast_exp2(e.z * L2E); se1.w = scaleF * fast_exp2(e.w * L2E);
      MiF += e0F;
      int rn = k + 4; if (rn > HALF - 1) rn = HALF - 1;
      erF[u][0] = *(const f32x4*)&eb[(size_t)rn * Kc + jb0];
      erF[u][1] = *(const f32x4*)&eb[(size_t)rn * Kc + jb1];
      f32x4 p;
      p.x = CF[0].x * se0.x; p.y = CF[0].y * se0.y;
      p.z = CF[0].z * se0.z; p.w = CF[0].w * se0.w;
      pf0 = p;
      uint32_t d0 = (uint32_t)(uint16_t)bf16rne(p.x) | ((uint32_t)(uint16_t)bf16rne(p.y) << 16);
      uint32_t d1 = (uint32_t)(uint16_t)bf16rne(p.z) | ((uint32_t)(uint16_t)bf16rne(p.w) << 16);
      *(uint2*)&pLF[buf][b][jb0] = make_uint2(d0, d1);
      p.x = CF[1].x * se1.x; p.y = CF[1].y * se1.y;
      p.z = CF[1].z * se1.z; p.w = CF[1].w * se1.w;
      pf1 = p;
      d0 = (uint32_t)(uint16_t)bf16rne(p.x) | ((uint32_t)(uint16_t)bf16rne(p.y) << 16);
      d1 = (uint32_t)(uint16_t)bf16rne(p.z) | ((uint32_t)(uint16_t)bf16rne(p.w) << 16);
      *(uint2*)&pLF[buf][b][jb1] = make_uint2(d0, d1);
      if (w == 0 && kq == 0) sScF[buf][b] = CF[0].x;
    }
    bar_lds();
#pragma unroll
    for (int tt = 0; tt < 4; ++tt)
      BfF[tt] = *(const bf16x8*)&pLF[buf][b][32 * tt + 8 * kq];
    {
      uint32_t ex = (__float_as_uint(sScF[buf][b]) >> 23) & 0xffu;
      e0F = (int)ex - 127;
      scaleF = __uint_as_float((254u - ex) << 23);
    }
  };

  for (int kb = 1; kb + 3 <= HALF - 1; kb += 4) {
    step_pair(kb, 0); step_pair(kb + 1, 1); step_pair(kb + 2, 2); step_pair(kb + 3, 3);
  }
  step_pair(HALF - 3, 0); step_pair(HALF - 2, 1); step_pair(HALF - 1, 2);

  // fwd: alpha_511 (includes ee_511).
  *(f32x4*)&ws[(size_t)brow * Kc + jb0] = pf0;
  *(f32x4*)&ws[(size_t)brow * Kc + jb1] = pf1;
  // bwd: CG = matvec #512 (v_512 = E w_512), scale only, NO emission.
  MiG += e0G;
  {
    f32x4 p0, p1;
    p0.x = CG[0].x * scaleG; p0.y = CG[0].y * scaleG;
    p0.z = CG[0].z * scaleG; p0.w = CG[0].w * scaleG;
    p1.x = CG[1].x * scaleG; p1.y = CG[1].y * scaleG;
    p1.z = CG[1].z * scaleG; p1.w = CG[1].w * scaleG;
    *(f32x4*)&ws[WS_PB + (size_t)brow * Kc + jb0] = p0;
    *(f32x4*)&ws[WS_PB + (size_t)brow * Kc + jb1] = p1;
  }
  if (tid < ROWS) {
    ws[WS_MIF + rb * ROWS + tid] = (float)MiF;   // thread tid: b == tid
    ws[WS_MIB + rb * ROWS + tid] = (float)MiG;
  }
}

// logZ_b = ln2 * (Mif + Mib + log2(sum_j pf[b][j] * pb[b][j]))
__global__ __launch_bounds__(64, 1) void crf_combine(
    const float* __restrict__ ws, float* __restrict__ out)
{
  const int b = (int)blockIdx.x;
  const int lane = (int)threadIdx.x;
  f2 pf = reinterpret_cast<const f2*>(ws + (size_t)b * Kc)[lane];
  f2 pb = reinterpret_cast<const f2*>(ws + WS_PB + (size_t)b * Kc)[lane];
  float v = pf.x * pb.x + pf.y * pb.y;
#pragma unroll
  for (int off = 32; off; off >>= 1) v += __shfl_down(v, off);
  if (lane == 0)
    out[b] = (ws[WS_MIF + b] + ws[WS_MIB + b] + fast_log2(v)) * LN2;
}

extern "C" void kernel_launch(void* const* d_in, const int* in_sizes, int n_in,
                              void* d_out, int out_size, void* d_ws, size_t ws_size,
                              hipStream_t stream) {
  const float* hs    = (const float*)d_in[0];
  const float* trans = (const float*)d_in[1];
  const float* st    = (const float*)d_in[2];
  const float* en    = (const float*)d_in[3];
  float* ws = (float*)d_ws;   // 66048 floats = 264192 B
  crf_fwd_bwd_kernel<<<dim3(Bc / ROWS), dim3(256), 0, stream>>>(hs, trans, st, en, ws);
  crf_combine<<<dim3(Bc), dim3(64), 0, stream>>>(ws, (float*)d_out);
}